// Round 9
// baseline (911.454 us; speedup 1.0000x reference)
//
#include <hip/hip_runtime.h>
#include <hip/hip_fp16.h>
#include <stdint.h>

typedef _Float16 f16;
typedef _Float16 f16x8 __attribute__((ext_vector_type(8)));
typedef float f32x4 __attribute__((ext_vector_type(4)));

#define NB 32768      // batch
#define LAYERS 6
#define AK 160        // HALF + COND
#define HID 1024

// async global->LDS, 16B per lane. LDS dest is wave-uniform base + lane*16.
__device__ __forceinline__ void async_copy16(const void* g, void* l) {
  __builtin_amdgcn_global_load_lds(
      (const __attribute__((address_space(1))) void*)g,
      (__attribute__((address_space(3))) void*)l, 16, 0, 0);
}

// ---------------------------------------------------------------------------
// Fused prep: batch state + 3 weight transposes in one kernel (R9, validated).
// ---------------------------------------------------------------------------
__device__ __forceinline__ void wtrans_tile(const float* __restrict__ W,
                                            f16* __restrict__ Wt,
                                            const int K_, const int N_,
                                            const int bx, const int by,
                                            const int bz, float (*t)[65])
{
  const long off = (long)bz * K_ * N_;
  const float* Wl = W + off;
  f16* Wtl = Wt + off;
  const int k0 = by * 64, n0 = bx * 64;
  const int tx = threadIdx.x & 63, ty4 = threadIdx.x >> 6;
#pragma unroll
  for (int r = ty4; r < 64; r += 4) {
    const int k = k0 + r;
    if (k < K_) t[r][tx] = Wl[(long)k * N_ + n0 + tx];
  }
  __syncthreads();
  const int k = k0 + tx;
  if (k < K_) {
#pragma unroll
    for (int r = ty4; r < 64; r += 4) {
      const int n = n0 + r;
      Wtl[(long)n * K_ + k] = (f16)t[tx][r];
    }
  }
}

__global__ void prep_all(const float* __restrict__ T, const float* __restrict__ cond,
                         const float* __restrict__ W1, const float* __restrict__ W2,
                         const float* __restrict__ W3,
                         float* __restrict__ z, float* __restrict__ ld,
                         f16* __restrict__ A,
                         f16* __restrict__ W1t, f16* __restrict__ W2t,
                         f16* __restrict__ W3t)
{
  __shared__ float t[64][65];
  const int b = blockIdx.x;
  if (b < 2048) {
    const int S1 = NB * 64;
    const int S2 = S1 + NB;
    const int S3 = S2 + NB * 32;
    const int S4 = S3 + NB * 128;
    for (int i = b * blockDim.x + threadIdx.x; i < S4; i += 2048 * blockDim.x) {
      if (i < S1) {
        z[i] = T[i];
      } else if (i < S2) {
        ld[i - S1] = 0.0f;
      } else if (i < S3) {
        int r = i - S2;
        int row = r >> 5, j = r & 31;
        A[(size_t)row * AK + j] = (f16)T[row * 64 + 32 + j];
      } else {
        int r = i - S3;
        int row = r >> 7, j = r & 127;
        A[(size_t)row * AK + 32 + j] = (f16)cond[r];
      }
    }
  } else if (b < 2048 + 288) {
    const int l = b - 2048;                      // 16 x 3 x 6
    wtrans_tile(W1, W1t, AK, 1024, l % 16, (l / 16) % 3, l / 48, t);
  } else if (b < 2048 + 288 + 1536) {
    const int l = b - (2048 + 288);              // 16 x 16 x 6
    wtrans_tile(W2, W2t, HID, 1024, l % 16, (l / 16) % 16, l / 256, t);
  } else {
    const int l = b - (2048 + 288 + 1536);       // 1 x 16 x 6
    wtrans_tile(W3, W3t, HID, 64, 0, l % 16, l / 16, t);
  }
}

// ---------------------------------------------------------------------------
// GEMM1 (K=160) R22 body unchanged (bounce epilogue, quad-XOR).
// ---------------------------------------------------------------------------
__global__ __launch_bounds__(256, 2)
void gemm1_full(const f16* __restrict__ A,
                const f16* __restrict__ Wt,       // 1024 x 160
                const float* __restrict__ bias,
                f16* __restrict__ C)
{
  __shared__ __align__(16) f16 As[128 * 160];     // 40 KB
  __shared__ __align__(16) f16 Bs[128 * 160];     // 40 KB
  const int tid  = threadIdx.x;
  const int lane = tid & 63;
  const int wave = tid >> 6;
  const int c15  = lane & 15;
  const int quad = lane >> 4;
  const int wm = (wave & 1) * 64;
  const int wn = (wave >> 1) * 64;

  const int b = blockIdx.x;
  const int x = b & 7, i = b >> 3;
  const long rowStart = (long)(x * 32 + (i >> 3)) * 128;
  const long colStart = (long)(i & 7) * 128;

  const f16* Ab = A  + rowStart * AK;
  const f16* Bb = Wt + colStart * AK;

#pragma unroll
  for (int it = 0; it < 10; ++it) {
    const int f = it * 256 + tid;
    const int row = f / 20;
    const int ch  = f - row * 20;
    const int chs = ch ^ ((row >> 1) & 3);
    async_copy16(Ab + (long)row * AK + chs * 8, &As[0] + (long)f * 8);
    async_copy16(Bb + (long)row * AK + chs * 8, &Bs[0] + (long)f * 8);
  }
  __syncthreads();

  f32x4 acc[4][4] = {};
#pragma unroll
  for (int kt = 0; kt < 5; ++kt) {
    f16x8 a[4], bf[4];
#pragma unroll
    for (int mi = 0; mi < 4; ++mi) {
      const int R = wm + mi * 16 + c15;
      a[mi] = *(const f16x8*)&As[(R * 20 + kt * 4 + (quad ^ ((R >> 1) & 3))) * 8];
    }
#pragma unroll
    for (int ni = 0; ni < 4; ++ni) {
      const int R = wn + ni * 16 + c15;
      bf[ni] = *(const f16x8*)&Bs[(R * 20 + kt * 4 + (quad ^ ((R >> 1) & 3))) * 8];
    }
#pragma unroll
    for (int mi = 0; mi < 4; ++mi)
#pragma unroll
      for (int ni = 0; ni < 4; ++ni)
        acc[mi][ni] = __builtin_amdgcn_mfma_f32_16x16x32_f16(
            a[mi], bf[ni], acc[mi][ni], 0, 0, 0);
  }

  // ---- Bounce epilogue: all waves done reading As after this barrier.
  __syncthreads();
  f16* Lp = &As[0] + wave * 4096;                 // 8 KB per wave, private
  const int erow = lane >> 3;                     // 0..7
  const int ec   = lane & 7;                      // 16B chunk in 64-col row
#pragma unroll
  for (int ni = 0; ni < 4; ++ni) {
    const long gn = colStart + wn + ni * 16 + c15;
    const float bv = bias[gn];
    const int lc = ni * 16 + c15;                 // logical col 0..63
#pragma unroll
    for (int mi = 0; mi < 4; ++mi) {
#pragma unroll
      for (int r = 0; r < 4; ++r) {
        const int R = mi * 16 + quad * 4 + r;
        float v = acc[mi][ni][r] + bv;
        Lp[R * 64 + (((lc >> 3) ^ (quad << 1)) << 3) + (lc & 7)] = (f16)fmaxf(v, 0.0f);
      }
    }
  }
  // wave-private patch: DS ops are wave-ordered, no barrier needed.
#pragma unroll
  for (int it = 0; it < 8; ++it) {
    const int R = it * 8 + erow;
    const int phys = ec ^ (((R >> 2) & 3) << 1);
    f16x8 rowv = *(const f16x8*)&Lp[R * 64 + (phys << 3)];
    *(f16x8*)&C[(rowStart + wm + R) * HID + colStart + wn + ec * 8] = rowv;
  }
}

// ---------------------------------------------------------------------------
// GEMM2 R23: single-phase BK=64 — 2 barriers/K-tile instead of 8. R8 audit:
// 5828 cyc/K-tile vs ~1700 floor; the gap tracks 8 barriers x ~450 cyc of
// lockstep skew/drain. This is the R16-V1 structure (hazard proof airtight;
// R17 proved it correct at BK=32) at the never-measured BK=64 cell:
//   reads 24 b128 (all operands) -> lgkm0 (own reads done, pre-barrier)
//   -> barrier (ALL waves done reading buf[sel])
//   -> stageFull(kt+2, sel)  (overwrite now provably safe)
//   -> 64 straight MFMA, zero waits (operands in regs)
//   -> vmcnt(8) [kt+1 landed; kt+2's 8 may fly] -> barrier.
// Tail: kt=14 -> no stage, vmcnt(0); kt=15 -> no wait. Per-accumulator FP
// order unchanged (kt asc, ks asc) -> absmax 0.25 canary. Epilogue =
// R22's quad-XOR bounce (0 conflicts, 64 MB writes, validated).
// ---------------------------------------------------------------------------
__global__ __launch_bounds__(512, 2)
void gemm2_v1b(const f16* __restrict__ A,         // 32768 x 1024 (X1)
               const f16* __restrict__ Wt,        // 1024 x 1024 (n-major)
               const float* __restrict__ bias,
               f16* __restrict__ C)               // 32768 x 1024 (X2)
{
  __shared__ __align__(16) f16 As[2][16384];      // 2 x 256x64
  __shared__ __align__(16) f16 Bs[2][16384];

  const int tid  = threadIdx.x;
  const int lane = tid & 63;
  const int wave = tid >> 6;
  const int c15  = lane & 15;
  const int quad = lane >> 4;
  const int wm = (wave >> 2) * 128;               // wave row base in tile
  const int wn = (wave & 3) * 64;                 // wave col base in tile

  // Bijective XCD swizzle (512 blocks, 512%8==0).
  const int b = blockIdx.x;
  const int wgid = (b & 7) * 64 + (b >> 3);
  const long rowStart = (long)(wgid >> 2) * 256;
  const long colStart = (long)(wgid & 3) * 256;

  const f16* Ab = A  + rowStart * HID;
  const f16* Bb = Wt + colStart * HID;

  const int rh0 = tid >> 3;
  const int ch0 = tid & 7;
  const long g0 = (long)rh0 * HID + ((ch0 ^ (rh0 & 7)) << 3);
  const long g1 = (long)(64 + rh0) * HID + ((ch0 ^ ((64 + rh0) & 7)) << 3);
  const int l0 = tid << 3;
  const int l1 = (512 + tid) << 3;

  auto stageFull = [&](int kt2, int sel) {
    const f16* sa = Ab + (long)kt2 * 64;
    const f16* sb = Bb + (long)kt2 * 64;
    f16* da = &As[sel][0];
    f16* db = &Bs[sel][0];
    async_copy16(sa + g0, da + l0);
    async_copy16(sa + (long)128 * HID + g0, da + 8192 + l0);
    async_copy16(sa + g1, da + l1);
    async_copy16(sa + (long)128 * HID + g1, da + 8192 + l1);
    async_copy16(sb + g0, db + l0);
    async_copy16(sb + (long)128 * HID + g0, db + 8192 + l0);
    async_copy16(sb + g1, db + l1);
    async_copy16(sb + (long)128 * HID + g1, db + 8192 + l1);
  };

  stageFull(0, 0);
  stageFull(1, 1);
  asm volatile("s_waitcnt vmcnt(8)" ::: "memory");   // kt0 landed
  __builtin_amdgcn_s_barrier();

  f32x4 acc[8][4] = {};

#pragma unroll 2
  for (int kt = 0; kt < 16; ++kt) {
    const int sel = kt & 1;
    const f16* as = &As[sel][0];
    const f16* bs = &Bs[sel][0];

    f16x8 a[8][2], bf[4][2];
#pragma unroll
    for (int m = 0; m < 8; ++m) {
      const int r = wm + m * 16 + c15;
#pragma unroll
      for (int ks = 0; ks < 2; ++ks)
        a[m][ks] = *(const f16x8*)&as[r * 64 + ((((ks << 2) + quad) ^ (r & 7)) << 3)];
    }
#pragma unroll
    for (int n = 0; n < 4; ++n) {
      const int r = wn + n * 16 + c15;
#pragma unroll
      for (int ks = 0; ks < 2; ++ks)
        bf[n][ks] = *(const f16x8*)&bs[r * 64 + ((((ks << 2) + quad) ^ (r & 7)) << 3)];
    }
    asm volatile("s_waitcnt lgkmcnt(0)" ::: "memory"); // own reads drained
    __builtin_amdgcn_s_barrier();                      // all waves done reading
    if (kt + 2 < 16) stageFull(kt + 2, sel);           // overwrite safe now
    __builtin_amdgcn_s_setprio(1);
#pragma unroll
    for (int ks = 0; ks < 2; ++ks)
#pragma unroll
      for (int m = 0; m < 8; ++m)
#pragma unroll
        for (int n = 0; n < 4; ++n)
          acc[m][n] = __builtin_amdgcn_mfma_f32_16x16x32_f16(
              a[m][ks], bf[n][ks], acc[m][n], 0, 0, 0);
    __builtin_amdgcn_s_setprio(0);
    if (kt + 2 < 16) {
      asm volatile("s_waitcnt vmcnt(8)" ::: "memory"); // kt+1 landed
    } else if (kt + 1 < 16) {
      asm volatile("s_waitcnt vmcnt(0)" ::: "memory"); // drain kt15
    }
    __builtin_amdgcn_s_barrier();
  }

  // ---- Epilogue: quad-XOR-swizzled LDS bounce -> f16x8 full-line stores.
  f16* Lp = &As[0][0] + wave * 1024;              // 2 KB per wave, private
  const int erow = lane >> 3;                     // 0..7
  const int ec   = lane & 7;                      // 16B chunk in 64-col row
  const int ecol8 = ec * 8;
  const long gcol = colStart + wn;
  const int q0x = ((erow >> 2) & 3) << 1;         // writer-quad XOR, row erow
  const int q1x = (((8 + erow) >> 2) & 3) << 1;   // row 8+erow
#pragma unroll
  for (int mii = 0; mii < 8; ++mii) {
    const int mof = (mii >> 2) * 64 + (mii & 3) * 16;
#pragma unroll
    for (int nii = 0; nii < 4; ++nii) {
      const int nof = (nii >> 1) * 32 + (nii & 1) * 16;
      const float bv = bias[gcol + nof + c15];
      const int lc = nof + c15;                   // logical col 0..63
#pragma unroll
      for (int r = 0; r < 4; ++r) {
        float v = acc[mii][nii][r] + bv;
        Lp[(quad * 4 + r) * 64 + (((lc >> 3) ^ (quad << 1)) << 3) + (lc & 7)]
            = (f16)fmaxf(v, 0.0f);
      }
    }
    // DS ops are wave-ordered: reads below see the writes above.
    f16x8 row0 = *(const f16x8*)&Lp[erow * 64 + ((ec ^ q0x) << 3)];
    f16x8 row1 = *(const f16x8*)&Lp[(8 + erow) * 64 + ((ec ^ q1x) << 3)];
    const long gm0 = rowStart + wm + mof + erow;
    *(f16x8*)&C[gm0 * HID + gcol + ecol8] = row0;
    *(f16x8*)&C[(gm0 + 8) * HID + gcol + ecol8] = row1;
  }
}

// ---------------------------------------------------------------------------
// GEMM3 (N=64) + coupling epilogue — R13 validated body, unchanged.
// ---------------------------------------------------------------------------
__global__ __launch_bounds__(256, 2)
void gemm3_coupling(const f16* __restrict__ X2, const f16* __restrict__ W3t,
                    const float* __restrict__ b3, float* __restrict__ z,
                    float* __restrict__ log_det, f16* __restrict__ Anext,
                    const int maskoff)
{
  __shared__ __align__(16) f16 As[2][64 * 64];    // 8 KB per buffer
  __shared__ __align__(16) f16 Bs[2][64 * 64];
  const int tid = threadIdx.x;
  const int wave = tid >> 6, lane = tid & 63;
  const int c15 = lane & 15, quad = lane >> 4;
  const int wm = wave * 16;
  const long rowStart = (long)blockIdx.x * 64;

  const f16* Ab = X2 + rowStart * HID;
  const int brow = tid >> 3;                       // 0..31 (+q*32)
  const int bkc  = ((tid & 7) ^ (brow & 7)) * 8;

  f32x4 acc[4] = {};

  auto stage = [&](int c, int sel) {
    const long kb = (long)c * 64;
#pragma unroll
    for (int q = 0; q < 2; ++q) {
      async_copy16(Ab  + (long)(q * 32 + brow) * HID + kb + bkc,
                   &As[sel][0] + (q * 256 + wave * 64) * 8);
      async_copy16(W3t + (long)(q * 32 + brow) * HID + kb + bkc,
                   &Bs[sel][0] + (q * 256 + wave * 64) * 8);
    }
  };

  stage(0, 0);
  for (int c = 0; c < 16; ++c) {
    __syncthreads();                 // drains stage(c), issued one step ago
    if (c + 1 < 16) stage(c + 1, (c + 1) & 1);
    const f16* as = &As[c & 1][0];
    const f16* bs = &Bs[c & 1][0];

#pragma unroll
    for (int s = 0; s < 2; ++s) {
      const int Ra = wm + c15;
      f16x8 a = *(const f16x8*)&as[(Ra * 8 + ((s * 4 + quad) ^ (Ra & 7))) * 8];
      f16x8 bf[4];
#pragma unroll
      for (int ni = 0; ni < 4; ++ni) {
        const int R = ni * 16 + c15;
        bf[ni] = *(const f16x8*)&bs[(R * 8 + ((s * 4 + quad) ^ (R & 7))) * 8];
      }
#pragma unroll
      for (int ni = 0; ni < 4; ++ni)
        acc[ni] = __builtin_amdgcn_mfma_f32_16x16x32_f16(a, bf[ni], acc[ni], 0, 0, 0);
    }
  }

  float sp[4] = {0.0f, 0.0f, 0.0f, 0.0f};
#pragma unroll
  for (int ni = 0; ni < 2; ++ni) {
    const int j = ni * 16 + c15;          // s-column 0..31
    const float bs = b3[j];
    const float bt = b3[32 + j];
#pragma unroll
    for (int r = 0; r < 4; ++r) {
      const long gm = rowStart + wm + quad * 4 + r;
      const float sv = acc[ni][r] + bs;
      const float e2 = __expf(2.0f * sv);            // tanh via exp
      const float s  = 1.0f - 2.0f / (e2 + 1.0f);
      const float tv = acc[ni + 2][r] + bt;
      const float m  = z[gm * 64 + maskoff + j];
      const float y  = fmaf(m, __expf(s), tv);
      z[gm * 64 + maskoff + j] = y;
      Anext[gm * AK + j] = (f16)y;   // next layer's unmasked input
      sp[r] += s;
    }
  }
#pragma unroll
  for (int r = 0; r < 4; ++r) {
    float v = sp[r];
    v += __shfl_xor(v, 1);
    v += __shfl_xor(v, 2);
    v += __shfl_xor(v, 4);
    v += __shfl_xor(v, 8);
    if (c15 == 0) {
      const long gm = rowStart + wm + quad * 4 + r;
      log_det[gm] += v;   // only this thread touches this row this layer
    }
  }
}

// ---------------------------------------------------------------------------
extern "C" void kernel_launch(void* const* d_in, const int* in_sizes, int n_in,
                              void* d_out, int out_size, void* d_ws, size_t ws_size,
                              hipStream_t stream) {
  (void)in_sizes; (void)n_in; (void)out_size; (void)ws_size;
  const float* T    = (const float*)d_in[0];
  const float* cond = (const float*)d_in[1];
  const float* W1   = (const float*)d_in[2];
  const float* b1   = (const float*)d_in[3];
  const float* W2   = (const float*)d_in[4];
  const float* b2   = (const float*)d_in[5];
  const float* W3   = (const float*)d_in[6];
  const float* b3   = (const float*)d_in[7];

  float* z  = (float*)d_out;                 // B x 64 working state = output
  float* ld = z + (size_t)NB * 64;           // B log_det

  f16* A   = (f16*)d_ws;                     // B x 160
  f16* X1  = A   + (size_t)NB * AK;          // B x 1024
  f16* X2  = X1  + (size_t)NB * HID;         // B x 1024
  f16* W1t = X2  + (size_t)NB * HID;         // 6 x 1024 x 160
  f16* W2t = W1t + (size_t)6 * 1024 * 160;   // 6 x 1024 x 1024
  f16* W3t = W2t + ((size_t)6 << 20);        // 6 x 64 x 1024

  prep_all<<<3968, 256, 0, stream>>>(T, cond, W1, W2, W3,
                                     z, ld, A, W1t, W2t, W3t);

  const int g1 = (NB / 128) * (HID / 128);   // 2048 blocks
  const int g2 = (NB / 256) * (HID / 256);   // 512 blocks
  for (int l = 0; l < LAYERS; ++l) {
    gemm1_full<<<g1, 256, 0, stream>>>(A, W1t + (size_t)l * 1024 * AK,
                                       b1 + l * 1024, X1);
    gemm2_v1b<<<g2, 512, 0, stream>>>(X1, W2t + ((size_t)l << 20),
                                      b2 + l * 1024, X2);
    const int maskoff = (l & 1) ? 32 : 0;
    gemm3_coupling<<<NB / 64, 256, 0, stream>>>(X2, W3t + (size_t)l * 64 * 1024,
                                                b3 + l * 64, z, ld, A, maskoff);
  }
}

// Round 10
// 728.531 us; speedup vs baseline: 1.2511x; 1.2511x over previous
//
#include <hip/hip_runtime.h>
#include <hip/hip_fp16.h>
#include <stdint.h>

typedef _Float16 f16;
typedef _Float16 f16x8 __attribute__((ext_vector_type(8)));
typedef float f32x4 __attribute__((ext_vector_type(4)));

#define NB 32768      // batch
#define LAYERS 6
#define AK 160        // HALF + COND
#define HID 1024

// async global->LDS, 16B per lane. LDS dest is wave-uniform base + lane*16.
__device__ __forceinline__ void async_copy16(const void* g, void* l) {
  __builtin_amdgcn_global_load_lds(
      (const __attribute__((address_space(1))) void*)g,
      (__attribute__((address_space(3))) void*)l, 16, 0, 0);
}

// ---------------------------------------------------------------------------
// Fused prep: batch state + 3 weight transposes in one kernel (R9, validated).
// ---------------------------------------------------------------------------
__device__ __forceinline__ void wtrans_tile(const float* __restrict__ W,
                                            f16* __restrict__ Wt,
                                            const int K_, const int N_,
                                            const int bx, const int by,
                                            const int bz, float (*t)[65])
{
  const long off = (long)bz * K_ * N_;
  const float* Wl = W + off;
  f16* Wtl = Wt + off;
  const int k0 = by * 64, n0 = bx * 64;
  const int tx = threadIdx.x & 63, ty4 = threadIdx.x >> 6;
#pragma unroll
  for (int r = ty4; r < 64; r += 4) {
    const int k = k0 + r;
    if (k < K_) t[r][tx] = Wl[(long)k * N_ + n0 + tx];
  }
  __syncthreads();
  const int k = k0 + tx;
  if (k < K_) {
#pragma unroll
    for (int r = ty4; r < 64; r += 4) {
      const int n = n0 + r;
      Wtl[(long)n * K_ + k] = (f16)t[tx][r];
    }
  }
}

__global__ void prep_all(const float* __restrict__ T, const float* __restrict__ cond,
                         const float* __restrict__ W1, const float* __restrict__ W2,
                         const float* __restrict__ W3,
                         float* __restrict__ z, float* __restrict__ ld,
                         f16* __restrict__ A,
                         f16* __restrict__ W1t, f16* __restrict__ W2t,
                         f16* __restrict__ W3t)
{
  __shared__ float t[64][65];
  const int b = blockIdx.x;
  if (b < 2048) {
    const int S1 = NB * 64;
    const int S2 = S1 + NB;
    const int S3 = S2 + NB * 32;
    const int S4 = S3 + NB * 128;
    for (int i = b * blockDim.x + threadIdx.x; i < S4; i += 2048 * blockDim.x) {
      if (i < S1) {
        z[i] = T[i];
      } else if (i < S2) {
        ld[i - S1] = 0.0f;
      } else if (i < S3) {
        int r = i - S2;
        int row = r >> 5, j = r & 31;
        A[(size_t)row * AK + j] = (f16)T[row * 64 + 32 + j];
      } else {
        int r = i - S3;
        int row = r >> 7, j = r & 127;
        A[(size_t)row * AK + 32 + j] = (f16)cond[r];
      }
    }
  } else if (b < 2048 + 288) {
    const int l = b - 2048;                      // 16 x 3 x 6
    wtrans_tile(W1, W1t, AK, 1024, l % 16, (l / 16) % 3, l / 48, t);
  } else if (b < 2048 + 288 + 1536) {
    const int l = b - (2048 + 288);              // 16 x 16 x 6
    wtrans_tile(W2, W2t, HID, 1024, l % 16, (l / 16) % 16, l / 256, t);
  } else {
    const int l = b - (2048 + 288 + 1536);       // 1 x 16 x 6
    wtrans_tile(W3, W3t, HID, 64, 0, l % 16, l / 16, t);
  }
}

// ---------------------------------------------------------------------------
// GEMM1 (K=160): validated R8 body, scalar epilogue (R7 config — best
// measured remainder; the R22 bounce was neutral-to-negative here).
// ---------------------------------------------------------------------------
__global__ __launch_bounds__(256, 2)
void gemm1_full(const f16* __restrict__ A,
                const f16* __restrict__ Wt,       // 1024 x 160
                const float* __restrict__ bias,
                f16* __restrict__ C)
{
  __shared__ __align__(16) f16 As[128 * 160];     // 40 KB
  __shared__ __align__(16) f16 Bs[128 * 160];     // 40 KB
  const int tid  = threadIdx.x;
  const int lane = tid & 63;
  const int wave = tid >> 6;
  const int c15  = lane & 15;
  const int quad = lane >> 4;
  const int wm = (wave & 1) * 64;
  const int wn = (wave >> 1) * 64;

  const int b = blockIdx.x;
  const int x = b & 7, i = b >> 3;
  const long rowStart = (long)(x * 32 + (i >> 3)) * 128;
  const long colStart = (long)(i & 7) * 128;

  const f16* Ab = A  + rowStart * AK;
  const f16* Bb = Wt + colStart * AK;

#pragma unroll
  for (int it = 0; it < 10; ++it) {
    const int f = it * 256 + tid;
    const int row = f / 20;
    const int ch  = f - row * 20;
    const int chs = ch ^ ((row >> 1) & 3);
    async_copy16(Ab + (long)row * AK + chs * 8, &As[0] + (long)f * 8);
    async_copy16(Bb + (long)row * AK + chs * 8, &Bs[0] + (long)f * 8);
  }
  __syncthreads();

  f32x4 acc[4][4] = {};
#pragma unroll
  for (int kt = 0; kt < 5; ++kt) {
    f16x8 a[4], bf[4];
#pragma unroll
    for (int mi = 0; mi < 4; ++mi) {
      const int R = wm + mi * 16 + c15;
      a[mi] = *(const f16x8*)&As[(R * 20 + kt * 4 + (quad ^ ((R >> 1) & 3))) * 8];
    }
#pragma unroll
    for (int ni = 0; ni < 4; ++ni) {
      const int R = wn + ni * 16 + c15;
      bf[ni] = *(const f16x8*)&Bs[(R * 20 + kt * 4 + (quad ^ ((R >> 1) & 3))) * 8];
    }
#pragma unroll
    for (int mi = 0; mi < 4; ++mi)
#pragma unroll
      for (int ni = 0; ni < 4; ++ni)
        acc[mi][ni] = __builtin_amdgcn_mfma_f32_16x16x32_f16(
            a[mi], bf[ni], acc[mi][ni], 0, 0, 0);
  }

#pragma unroll
  for (int ni = 0; ni < 4; ++ni) {
    const long gn = colStart + wn + ni * 16 + c15;
    const float bv = bias[gn];
#pragma unroll
    for (int mi = 0; mi < 4; ++mi) {
#pragma unroll
      for (int r = 0; r < 4; ++r) {
        const long gm = rowStart + wm + mi * 16 + quad * 4 + r;
        float v = acc[mi][ni][r] + bv;
        v = fmaxf(v, 0.0f);
        C[gm * HID + gn] = (f16)v;
      }
    }
  }
}

// ---------------------------------------------------------------------------
// GEMM2 R24 = R22 verbatim: 8-phase loop (best deterministic schedule of 7
// tried: 77.6 us / 884 TF / MfmaUtil 37) + quad-XOR bounce epilogue
// (0 bank conflicts, WRITE_SIZE = 64 MB ideal). R23's single-phase BK=64
// spilled (FETCH/WRITE jump + VGPR cap) — deeper variants are register-
// infeasible at this tile; banking this plateau.
// ---------------------------------------------------------------------------
__global__ __launch_bounds__(512, 2)
void gemm2_ep(const f16* __restrict__ A,          // 32768 x 1024 (X1)
              const f16* __restrict__ Wt,         // 1024 x 1024 (n-major)
              const float* __restrict__ bias,
              f16* __restrict__ C)                // 32768 x 1024 (X2)
{
  __shared__ __align__(16) f16 As[2][16384];      // 2 x 256x64
  __shared__ __align__(16) f16 Bs[2][16384];

  const int tid  = threadIdx.x;
  const int lane = tid & 63;
  const int wave = tid >> 6;
  const int c15  = lane & 15;
  const int quad = lane >> 4;
  const int wm = (wave >> 2) * 128;               // wave row base in tile
  const int wn = (wave & 3) * 64;                 // wave col base in tile

  // Bijective XCD swizzle (512 blocks, 512%8==0).
  const int b = blockIdx.x;
  const int wgid = (b & 7) * 64 + (b >> 3);
  const long rowStart = (long)(wgid >> 2) * 256;
  const long colStart = (long)(wgid & 3) * 256;

  const f16* Ab = A  + rowStart * HID;
  const f16* Bb = Wt + colStart * HID;

  const int rh0 = tid >> 3;
  const int ch0 = tid & 7;
  const long g0 = (long)rh0 * HID + ((ch0 ^ (rh0 & 7)) << 3);
  const long g1 = (long)(64 + rh0) * HID + ((ch0 ^ ((64 + rh0) & 7)) << 3);
  const int l0 = tid << 3;
  const int l1 = (512 + tid) << 3;

  auto stageA = [&](int kt2, int h, int sel) {
    const f16* src = Ab + (long)h * 128 * HID + (long)kt2 * 64;
    f16* dst = &As[sel][h * 8192];
    async_copy16(src + g0, dst + l0);
    async_copy16(src + g1, dst + l1);
  };
  auto stageB = [&](int kt2, int h, int sel) {
    const f16* src = Bb + (long)h * 128 * HID + (long)kt2 * 64;
    f16* dst = &Bs[sel][h * 8192];
    async_copy16(src + g0, dst + l0);
    async_copy16(src + g1, dst + l1);
  };

  // Prologue (R14): kt0 fully + kt1's B0,A0. vmcnt(4): kt0 landed.
  stageA(0, 0, 0); stageA(0, 1, 0);
  stageB(0, 0, 0); stageB(0, 1, 0);
  stageB(1, 0, 1); stageA(1, 0, 1);
  asm volatile("s_waitcnt vmcnt(4)" ::: "memory");
  __builtin_amdgcn_s_barrier();
  __builtin_amdgcn_sched_barrier(0);

  f32x4 acc[8][4] = {};

#pragma unroll 2
  for (int kt = 0; kt < 16; ++kt) {
    const int sel = kt & 1;
    const f16* as = &As[sel][0];
    const f16* bs = &Bs[sel][0];
    const bool s1 = (kt + 1 < 16);
    const bool s2 = (kt + 2 < 16);
    f16x8 a0[4][2], a1[4][2], b0[2][2], b1[2][2];

    // ---- P1: read a0,b0; stage A1(kt+1) -> buf^1.
#pragma unroll
    for (int mi = 0; mi < 4; ++mi) {
      const int r = wm + mi * 16 + c15;
#pragma unroll
      for (int ks = 0; ks < 2; ++ks)
        a0[mi][ks] = *(const f16x8*)&as[r * 64 + ((((ks << 2) + quad) ^ (r & 7)) << 3)];
    }
#pragma unroll
    for (int ni = 0; ni < 2; ++ni) {
      const int r = wn + ni * 16 + c15;
#pragma unroll
      for (int ks = 0; ks < 2; ++ks)
        b0[ni][ks] = *(const f16x8*)&bs[r * 64 + ((((ks << 2) + quad) ^ (r & 7)) << 3)];
    }
    if (s1) stageA(kt + 1, 1, sel ^ 1);
    __builtin_amdgcn_s_barrier();
    asm volatile("s_waitcnt lgkmcnt(0)" ::: "memory");
    __builtin_amdgcn_sched_barrier(0);
    __builtin_amdgcn_s_setprio(1);
#pragma unroll
    for (int mi = 0; mi < 4; ++mi)
#pragma unroll
      for (int ni = 0; ni < 2; ++ni)
#pragma unroll
        for (int ks = 0; ks < 2; ++ks)
          acc[mi][ni] = __builtin_amdgcn_mfma_f32_16x16x32_f16(
              a0[mi][ks], b0[ni][ks], acc[mi][ni], 0, 0, 0);
    __builtin_amdgcn_s_setprio(0);
    __builtin_amdgcn_sched_barrier(0);
    __builtin_amdgcn_s_barrier();

    // ---- P2: read b1; stage B1(kt+1) -> buf^1.
#pragma unroll
    for (int ni = 0; ni < 2; ++ni) {
      const int r = wn + 32 + ni * 16 + c15;
#pragma unroll
      for (int ks = 0; ks < 2; ++ks)
        b1[ni][ks] = *(const f16x8*)&bs[r * 64 + ((((ks << 2) + quad) ^ (r & 7)) << 3)];
    }
    if (s1) stageB(kt + 1, 1, sel ^ 1);
    __builtin_amdgcn_s_barrier();
    asm volatile("s_waitcnt lgkmcnt(0)" ::: "memory");
    __builtin_amdgcn_sched_barrier(0);
    __builtin_amdgcn_s_setprio(1);
#pragma unroll
    for (int mi = 0; mi < 4; ++mi)
#pragma unroll
      for (int ni = 0; ni < 2; ++ni)
#pragma unroll
        for (int ks = 0; ks < 2; ++ks)
          acc[mi][2 + ni] = __builtin_amdgcn_mfma_f32_16x16x32_f16(
              a0[mi][ks], b1[ni][ks], acc[mi][2 + ni], 0, 0, 0);
    __builtin_amdgcn_s_setprio(0);
    __builtin_amdgcn_sched_barrier(0);
    __builtin_amdgcn_s_barrier();

    // ---- P3: read a1; stage B0(kt+2) -> current buf.
#pragma unroll
    for (int mi = 0; mi < 4; ++mi) {
      const int r = wm + 64 + mi * 16 + c15;
#pragma unroll
      for (int ks = 0; ks < 2; ++ks)
        a1[mi][ks] = *(const f16x8*)&as[r * 64 + ((((ks << 2) + quad) ^ (r & 7)) << 3)];
    }
    if (s2) stageB(kt + 2, 0, sel);
    __builtin_amdgcn_s_barrier();
    asm volatile("s_waitcnt lgkmcnt(0)" ::: "memory");
    __builtin_amdgcn_sched_barrier(0);
    __builtin_amdgcn_s_setprio(1);
#pragma unroll
    for (int mi = 0; mi < 4; ++mi)
#pragma unroll
      for (int ni = 0; ni < 2; ++ni)
#pragma unroll
        for (int ks = 0; ks < 2; ++ks)
          acc[4 + mi][ni] = __builtin_amdgcn_mfma_f32_16x16x32_f16(
              a1[mi][ks], b0[ni][ks], acc[4 + mi][ni], 0, 0, 0);
    __builtin_amdgcn_s_setprio(0);
    __builtin_amdgcn_sched_barrier(0);
    __builtin_amdgcn_s_barrier();

    // ---- P4: stage A0(kt+2) -> current buf; vmcnt.
    if (s2) stageA(kt + 2, 0, sel);
    __builtin_amdgcn_s_setprio(1);
#pragma unroll
    for (int mi = 0; mi < 4; ++mi)
#pragma unroll
      for (int ni = 0; ni < 2; ++ni)
#pragma unroll
        for (int ks = 0; ks < 2; ++ks)
          acc[4 + mi][2 + ni] = __builtin_amdgcn_mfma_f32_16x16x32_f16(
              a1[mi][ks], b1[ni][ks], acc[4 + mi][2 + ni], 0, 0, 0);
    __builtin_amdgcn_s_setprio(0);
    if (s2) {
      asm volatile("s_waitcnt vmcnt(4)" ::: "memory");   // kt+1 fully landed
    } else if (s1) {
      asm volatile("s_waitcnt vmcnt(0)" ::: "memory");   // kt=14: drain kt15
    }
    __builtin_amdgcn_sched_barrier(0);
    __builtin_amdgcn_s_barrier();
  }

  // ---- Epilogue: quad-XOR-swizzled LDS bounce -> f16x8 full-line stores.
  f16* Lp = &As[0][0] + wave * 1024;              // 2 KB per wave, private
  const int erow = lane >> 3;                     // 0..7
  const int ec   = lane & 7;                      // 16B chunk in 64-col row
  const int ecol8 = ec * 8;
  const long gcol = colStart + wn;
  const int q0x = ((erow >> 2) & 3) << 1;         // writer-quad XOR, row erow
  const int q1x = (((8 + erow) >> 2) & 3) << 1;   // row 8+erow
#pragma unroll
  for (int mii = 0; mii < 8; ++mii) {
    const int mof = (mii >> 2) * 64 + (mii & 3) * 16;
#pragma unroll
    for (int nii = 0; nii < 4; ++nii) {
      const int nof = (nii >> 1) * 32 + (nii & 1) * 16;
      const float bv = bias[gcol + nof + c15];
      const int lc = nof + c15;                   // logical col 0..63
#pragma unroll
      for (int r = 0; r < 4; ++r) {
        float v = acc[mii][nii][r] + bv;
        Lp[(quad * 4 + r) * 64 + (((lc >> 3) ^ (quad << 1)) << 3) + (lc & 7)]
            = (f16)fmaxf(v, 0.0f);
      }
    }
    // DS ops are wave-ordered: reads below see the writes above.
    f16x8 row0 = *(const f16x8*)&Lp[erow * 64 + ((ec ^ q0x) << 3)];
    f16x8 row1 = *(const f16x8*)&Lp[(8 + erow) * 64 + ((ec ^ q1x) << 3)];
    const long gm0 = rowStart + wm + mof + erow;
    *(f16x8*)&C[gm0 * HID + gcol + ecol8] = row0;
    *(f16x8*)&C[(gm0 + 8) * HID + gcol + ecol8] = row1;
  }
}

// ---------------------------------------------------------------------------
// GEMM3 (N=64) + coupling R24: counted-vmcnt double-buffer (gemm2-proven
// discipline). Old loop: __syncthreads() = full vmcnt(0) drain per iter with
// only 1-iter prefetch; work/iter (~350 cyc) << DMA latency (~500-900) =>
// ~500 cyc stall x 16 iters. New: raw barriers, stage(c+2) 2-ahead, vmcnt(4)
// keeps newest stage in flight. Hazard ledger: reads of buf[sel] lgkm-
// drained PRE-barrier -> stage(c+2,sel) post-barrier can't race; in-flight
// DMA during reads targets buf[sel^1] only; vmcnt(4) -> stage(c+1) landed
// (FIFO); tail c=14 -> vmcnt(0), c=15 -> none. Read/MFMA order per acc
// element unchanged -> absmax 0.25 canary.
// ---------------------------------------------------------------------------
__global__ __launch_bounds__(256, 2)
void gemm3_coupling(const f16* __restrict__ X2, const f16* __restrict__ W3t,
                    const float* __restrict__ b3, float* __restrict__ z,
                    float* __restrict__ log_det, f16* __restrict__ Anext,
                    const int maskoff)
{
  __shared__ __align__(16) f16 As[2][64 * 64];    // 8 KB per buffer
  __shared__ __align__(16) f16 Bs[2][64 * 64];
  const int tid = threadIdx.x;
  const int wave = tid >> 6, lane = tid & 63;
  const int c15 = lane & 15, quad = lane >> 4;
  const int wm = wave * 16;
  const long rowStart = (long)blockIdx.x * 64;

  const f16* Ab = X2 + rowStart * HID;
  const int brow = tid >> 3;                       // 0..31 (+q*32)
  const int bkc  = ((tid & 7) ^ (brow & 7)) * 8;

  f32x4 acc[4] = {};

  auto stage = [&](int c, int sel) {
    const long kb = (long)c * 64;
#pragma unroll
    for (int q = 0; q < 2; ++q) {
      async_copy16(Ab  + (long)(q * 32 + brow) * HID + kb + bkc,
                   &As[sel][0] + (q * 256 + wave * 64) * 8);
      async_copy16(W3t + (long)(q * 32 + brow) * HID + kb + bkc,
                   &Bs[sel][0] + (q * 256 + wave * 64) * 8);
    }
  };

  // Prologue: 2-deep prefetch. vmcnt(4): stage(0)'s 4 landed, stage(1) flies.
  stage(0, 0);
  stage(1, 1);
  asm volatile("s_waitcnt vmcnt(4)" ::: "memory");
  __builtin_amdgcn_s_barrier();

  for (int c = 0; c < 16; ++c) {
    const int sel = c & 1;
    const f16* as = &As[sel][0];
    const f16* bs = &Bs[sel][0];

    // Reads (same order as validated R13 body: s=0 {a, bf0..3}, s=1 {...}).
    f16x8 av[2], bv[2][4];
#pragma unroll
    for (int s = 0; s < 2; ++s) {
      const int Ra = wm + c15;
      av[s] = *(const f16x8*)&as[(Ra * 8 + ((s * 4 + quad) ^ (Ra & 7))) * 8];
#pragma unroll
      for (int ni = 0; ni < 4; ++ni) {
        const int R = ni * 16 + c15;
        bv[s][ni] = *(const f16x8*)&bs[(R * 8 + ((s * 4 + quad) ^ (R & 7))) * 8];
      }
    }
    asm volatile("s_waitcnt lgkmcnt(0)" ::: "memory");  // own reads retired
    __builtin_amdgcn_s_barrier();                       // all waves done
    if (c + 2 < 16) stage(c + 2, sel);                  // overwrite safe now

#pragma unroll
    for (int s = 0; s < 2; ++s)
#pragma unroll
      for (int ni = 0; ni < 4; ++ni)
        acc[ni] = __builtin_amdgcn_mfma_f32_16x16x32_f16(av[s], bv[s][ni],
                                                         acc[ni], 0, 0, 0);
    if (c + 2 < 16) {
      asm volatile("s_waitcnt vmcnt(4)" ::: "memory");  // stage(c+1) landed
    } else if (c + 1 < 16) {
      asm volatile("s_waitcnt vmcnt(0)" ::: "memory");  // drain stage(15)
    }
    __builtin_amdgcn_s_barrier();
  }

  float sp[4] = {0.0f, 0.0f, 0.0f, 0.0f};
#pragma unroll
  for (int ni = 0; ni < 2; ++ni) {
    const int j = ni * 16 + c15;          // s-column 0..31
    const float bs = b3[j];
    const float bt = b3[32 + j];
#pragma unroll
    for (int r = 0; r < 4; ++r) {
      const long gm = rowStart + wm + quad * 4 + r;
      const float sv = acc[ni][r] + bs;
      const float e2 = __expf(2.0f * sv);            // tanh via exp
      const float s  = 1.0f - 2.0f / (e2 + 1.0f);
      const float tv = acc[ni + 2][r] + bt;
      const float m  = z[gm * 64 + maskoff + j];
      const float y  = fmaf(m, __expf(s), tv);
      z[gm * 64 + maskoff + j] = y;
      Anext[gm * AK + j] = (f16)y;   // next layer's unmasked input
      sp[r] += s;
    }
  }
#pragma unroll
  for (int r = 0; r < 4; ++r) {
    float v = sp[r];
    v += __shfl_xor(v, 1);
    v += __shfl_xor(v, 2);
    v += __shfl_xor(v, 4);
    v += __shfl_xor(v, 8);
    if (c15 == 0) {
      const long gm = rowStart + wm + quad * 4 + r;
      log_det[gm] += v;   // only this thread touches this row this layer
    }
  }
}

// ---------------------------------------------------------------------------
extern "C" void kernel_launch(void* const* d_in, const int* in_sizes, int n_in,
                              void* d_out, int out_size, void* d_ws, size_t ws_size,
                              hipStream_t stream) {
  (void)in_sizes; (void)n_in; (void)out_size; (void)ws_size;
  const float* T    = (const float*)d_in[0];
  const float* cond = (const float*)d_in[1];
  const float* W1   = (const float*)d_in[2];
  const float* b1   = (const float*)d_in[3];
  const float* W2   = (const float*)d_in[4];
  const float* b2   = (const float*)d_in[5];
  const float* W3   = (const float*)d_in[6];
  const float* b3   = (const float*)d_in[7];

  float* z  = (float*)d_out;                 // B x 64 working state = output
  float* ld = z + (size_t)NB * 64;           // B log_det

  f16* A   = (f16*)d_ws;                     // B x 160
  f16* X1  = A   + (size_t)NB * AK;          // B x 1024
  f16* X2  = X1  + (size_t)NB * HID;         // B x 1024
  f16* W1t = X2  + (size_t)NB * HID;         // 6 x 1024 x 160
  f16* W2t = W1t + (size_t)6 * 1024 * 160;   // 6 x 1024 x 1024
  f16* W3t = W2t + ((size_t)6 << 20);        // 6 x 64 x 1024

  prep_all<<<3968, 256, 0, stream>>>(T, cond, W1, W2, W3,
                                     z, ld, A, W1t, W2t, W3t);

  const int g1 = (NB / 128) * (HID / 128);   // 2048 blocks
  const int g2 = (NB / 256) * (HID / 256);   // 512 blocks
  for (int l = 0; l < LAYERS; ++l) {
    gemm1_full<<<g1, 256, 0, stream>>>(A, W1t + (size_t)l * 1024 * AK,
                                       b1 + l * 1024, X1);
    gemm2_ep<<<g2, 512, 0, stream>>>(X1, W2t + ((size_t)l << 20),
                                     b2 + l * 1024, X2);
    const int maskoff = (l & 1) ? 32 : 0;
    gemm3_coupling<<<NB / 64, 256, 0, stream>>>(X2, W3t + (size_t)l * 64 * 1024,
                                                b3 + l * 64, z, ld, A, maskoff);
  }
}